// Round 3
// baseline (1041.950 us; speedup 1.0000x reference)
//
#include <hip/hip_runtime.h>
#include <hip/hip_bf16.h>

// Problem constants
#define B 16
#define LP 128
#define LM 256
#define V 32000
#define E 512
#define H 512
#define DENC 1024          // 2*H
#define K1 2560            // E + 2*DENC
#define G4 2048            // 4*H

// d_out offsets (floats)
#define OFF_LOGITS 0
#define OFF_PW 512000
#define OFF_MW 514048
#define OFF_CTX 518144
#define OFF_H1 550912
#define OFF_C1 559104
#define OFF_H2 567296
#define OFF_C2 575488
#define OFF_H3 583680
#define OFF_C3 591872
#define OFF_H4 600064
#define OFF_C4 608256

#define ZSPLIT 32          // k-chunks for LSTM z GEMM
#define LSPLIT 8           // k-chunks for logits GEMM

// ws offsets (floats)
#define WS_X      0                      // B*K1 = 40960
#define WS_ZPART  40960                  // ZSPLIT*B*G4 = 1048576
#define WS_D2P    1089536                // B*H = 8192
#define WS_D2M    1097728                // B*H = 8192
#define WS_SP     1105920                // B*LP = 2048
#define WS_SM     1107968                // B*LM = 4096
#define WS_XXT    1112064                // K1*B = 40960 ([k][b])
#define WS_LPART  1153024                // LSPLIT*B*V = 4096000
#define WS_ENCBF  5249024                // 6291456 bf16 = 3145728 float slots
#define WS_W1T    8394752                // 2*512*1024 bf16 = 524288 float slots
// total ~8.92M floats = 35.7 MB

#define ENCM_BF_OFF 2097152              // bf16 offset of encM within ENCBF
#define W1TM_OFF    524288               // bf16 offset of msg W1T

typedef __attribute__((ext_vector_type(8))) short bhalf8;   // 8 bf16 (4 VGPRs)
typedef __attribute__((ext_vector_type(4))) float f32x4;

__device__ __forceinline__ float sigm(float x) { return 1.0f / (1.0f + expf(-x)); }

// ---------------- bf16 conversion of enc_persona / enc_msg ----------------
__global__ void k_cvt_enc(const float* __restrict__ encP, const float* __restrict__ encM,
                          __hip_bfloat16* __restrict__ encbf)
{
    int which = blockIdx.y;
    const float* src = which ? encM : encP;
    __hip_bfloat16* dst = encbf + (which ? ENCM_BF_OFF : 0);
    int n4 = (which ? B * LM * DENC : B * LP * DENC) / 4;
    int i = blockIdx.x * 256 + threadIdx.x;
    if (i < n4) {
        float4 v = ((const float4*)src)[i];
        __hip_bfloat16 o[4] = { __float2bfloat16(v.x), __float2bfloat16(v.y),
                                __float2bfloat16(v.z), __float2bfloat16(v.w) };
        *(short4*)&dst[i * 4] = *(short4*)o;
    }
}

// ---------------- transpose + convert W1 (1024x512 fp32) -> W1T (512x1024 bf16) ----------------
__global__ void k_cvtT(const float* __restrict__ pW1w, const float* __restrict__ mW1w,
                       __hip_bfloat16* __restrict__ w1t)
{
    __shared__ float tile[64][65];
    int which = blockIdx.z;
    const float* src = which ? mW1w : pW1w;
    __hip_bfloat16* dst = w1t + (which ? W1TM_OFF : 0);
    int k0 = blockIdx.x * 64, j0 = blockIdx.y * 64;
    for (int it = 0; it < 16; ++it) {
        int idx = it * 256 + threadIdx.x;
        int jj = idx & 63, kk = idx >> 6;
        tile[kk][jj] = src[(size_t)(k0 + kk) * H + j0 + jj];
    }
    __syncthreads();
    for (int it = 0; it < 16; ++it) {
        int idx = it * 256 + threadIdx.x;
        int kk = idx & 63, jj = idx >> 6;
        dst[(size_t)(j0 + jj) * DENC + k0 + kk] = __float2bfloat16(tile[kk][jj]);
    }
}

// ---------------- embedding gather + concat([ctx, emb]) ----------------
__global__ void k_embed(const int* __restrict__ word, const float* __restrict__ ctx,
                        const float* __restrict__ emb, float* __restrict__ x)
{
    int b = blockIdx.x;
    int w = word[b];
    for (int i = threadIdx.x; i < 2 * DENC; i += 256) x[b * K1 + i] = ctx[b * 2 * DENC + i];
    for (int i = threadIdx.x; i < E; i += 256)        x[b * K1 + 2 * DENC + i] = emb[(size_t)w * E + i];
}

// ---------------- z partials: zpart[s][b][j] = sum_{k in chunk s} in[b][k] * W[k][j] ----------------
__global__ void k_lstm_zp(const float* __restrict__ x, int kx,
                          const float* __restrict__ h,
                          const float* __restrict__ Wx, const float* __restrict__ Wh,
                          float* __restrict__ zpart)
{
    int j = blockIdx.x * 256 + threadIdx.x;
    int K = kx + H;
    int chunk = K / ZSPLIT;                        // 96 (L1) or 32 (L2-4)
    int k0 = blockIdx.y * chunk;
    int k1 = k0 + chunk;

    __shared__ float xs[96 * 16];                  // [k - k0][b]
    for (int idx = threadIdx.x; idx < chunk * 16; idx += 256) {
        int kk = idx >> 4, b = idx & 15;
        int k = k0 + kk;
        xs[idx] = (k < kx) ? x[b * kx + k] : h[b * H + (k - kx)];
    }
    __syncthreads();

    float acc[16];
    #pragma unroll
    for (int b = 0; b < 16; ++b) acc[b] = 0.f;

    #pragma unroll 4
    for (int k = k0; k < k1; ++k) {
        float w = (k < kx) ? Wx[(size_t)k * G4 + j] : Wh[(size_t)(k - kx) * G4 + j];
        const float4* xp = (const float4*)&xs[(k - k0) * 16];
        float4 x0 = xp[0], x1 = xp[1], x2 = xp[2], x3 = xp[3];
        acc[0]  += x0.x * w; acc[1]  += x0.y * w; acc[2]  += x0.z * w; acc[3]  += x0.w * w;
        acc[4]  += x1.x * w; acc[5]  += x1.y * w; acc[6]  += x1.z * w; acc[7]  += x1.w * w;
        acc[8]  += x2.x * w; acc[9]  += x2.y * w; acc[10] += x2.z * w; acc[11] += x2.w * w;
        acc[12] += x3.x * w; acc[13] += x3.y * w; acc[14] += x3.z * w; acc[15] += x3.w * w;
    }

    float* zp = zpart + (size_t)blockIdx.y * B * G4;
    #pragma unroll
    for (int b = 0; b < 16; ++b) zp[b * G4 + j] = acc[b];
}

// ---------------- gates: reduce partials + bias, LSTM nonlinearity; layer4 also fills XXT ----------------
__global__ void k_gates(const float* __restrict__ zpart, const float* __restrict__ bias,
                        const float* __restrict__ c_old,
                        float* __restrict__ h_new, float* __restrict__ c_new,
                        float* __restrict__ xxt)
{
    int b = blockIdx.y;
    int j = blockIdx.x * 256 + threadIdx.x;
    float zi = bias[j], zf = bias[H + j], zg = bias[2 * H + j], zo = bias[3 * H + j];
    #pragma unroll
    for (int s = 0; s < ZSPLIT; ++s) {
        const float* zp = zpart + ((size_t)s * B + b) * G4;
        zi += zp[j]; zf += zp[H + j]; zg += zp[2 * H + j]; zo += zp[3 * H + j];
    }
    float c = sigm(zf) * c_old[b * H + j] + sigm(zi) * tanhf(zg);
    float hh = sigm(zo) * tanhf(c);
    c_new[b * H + j] = c;
    h_new[b * H + j] = hh;
    if (xxt) xxt[j * 16 + b] = hh;                 // h4 part of xx^T
}

// ---------------- d2 = h4@W2 + W2b  (both attentions) ----------------
__global__ void k_decproj(const float* __restrict__ h4,
                          const float* __restrict__ pW2w, const float* __restrict__ pW2b,
                          const float* __restrict__ mW2w, const float* __restrict__ mW2b,
                          float* __restrict__ d2p, float* __restrict__ d2m)
{
    int b = blockIdx.y;
    int j = blockIdx.x * 256 + threadIdx.x;
    int which = blockIdx.z;
    const float* W = which ? mW2w : pW2w;
    const float* bb = which ? mW2b : pW2b;
    float* o = which ? d2m : d2p;
    const float* hr = h4 + b * H;
    float acc = bb[j];
    #pragma unroll 8
    for (int k = 0; k < H; ++k) acc += hr[k] * W[k * H + j];
    o[b * H + j] = acc;
}

// ---------------- MFMA attention scores ----------------
// s[b,l] = sum_j tanh( (enc@W1)[l,j] + W1b[j] + d2[b,j] ) * Vw[j] + Vb
// A = enc_bf rows (l,k); B = W1T rows (j,k).  16x16x32 bf16 MFMA.
// grid.x: 32 persona blocks (b*2+lt) then 64 msg blocks (b*4+lt); 64 rows/block, 16 rows/wave.
__global__ void k_attscore_mfma(const __hip_bfloat16* __restrict__ encbf,
                                const __hip_bfloat16* __restrict__ w1t,
                                const float* __restrict__ pW1b, const float* __restrict__ pVw,
                                const float* __restrict__ pVb,
                                const float* __restrict__ mW1b, const float* __restrict__ mVw,
                                const float* __restrict__ mVb,
                                const float* __restrict__ d2p, const float* __restrict__ d2m,
                                float* __restrict__ sp, float* __restrict__ sm)
{
    int t = blockIdx.x;
    int b, lt, L;
    const __hip_bfloat16 *enc, *wt;
    const float *w1b, *vw, *vb, *d2;
    float* sout;
    if (t < 32) { b = t >> 1; lt = t & 1; L = LP; enc = encbf; wt = w1t;
                  w1b = pW1b; vw = pVw; vb = pVb; d2 = d2p; sout = sp; }
    else { int u = t - 32; b = u >> 2; lt = u & 3; L = LM; enc = encbf + ENCM_BF_OFF;
           wt = w1t + W1TM_OFF; w1b = mW1b; vw = mVw; vb = mVb; d2 = d2m; sout = sm; }

    int wave = threadIdx.x >> 6, lane = threadIdx.x & 63;
    int m = lane & 15, quad = lane >> 4;
    int row0 = lt * 64 + wave * 16;                // l offset of this wave's 16 rows

    const __hip_bfloat16* arow = enc + (size_t)(b * L + row0 + m) * DENC + quad * 8;

    f32x4 acc[32];
    #pragma unroll
    for (int nt = 0; nt < 32; ++nt) acc[nt] = (f32x4){0.f, 0.f, 0.f, 0.f};

    for (int kt = 0; kt < 32; ++kt) {
        bhalf8 a = *(const bhalf8*)(arow + kt * 32);
        #pragma unroll
        for (int nt = 0; nt < 32; ++nt) {
            bhalf8 bf = *(const bhalf8*)(wt + (size_t)(nt * 16 + m) * DENC + kt * 32 + quad * 8);
            acc[nt] = __builtin_amdgcn_mfma_f32_16x16x32_bf16(a, bf, acc[nt], 0, 0, 0);
        }
    }

    // epilogue: tanh(+W1b+d2)*Vw, reduce over j
    float sacc[4] = {0.f, 0.f, 0.f, 0.f};
    #pragma unroll
    for (int nt = 0; nt < 32; ++nt) {
        int j = nt * 16 + m;
        float cadd = w1b[j] + d2[b * H + j];
        float vv = vw[j];
        #pragma unroll
        for (int r = 0; r < 4; ++r) sacc[r] += tanhf(acc[nt][r] + cadd) * vv;
    }
    #pragma unroll
    for (int off = 1; off < 16; off <<= 1) {
        #pragma unroll
        for (int r = 0; r < 4; ++r) sacc[r] += __shfl_xor(sacc[r], off);
    }
    if (m == 0) {
        float v0 = vb[0];
        #pragma unroll
        for (int r = 0; r < 4; ++r)
            sout[b * L + row0 + quad * 4 + r] = sacc[r] + v0;   // row = quad*4 + r
    }
}

// ---------------- softmax over L, writes p_w / m_w to d_out ----------------
__global__ void k_softmax(const float* __restrict__ sp, const float* __restrict__ sm,
                          float* __restrict__ out)
{
    int b = blockIdx.x, which = blockIdx.y, tid = threadIdx.x;
    const float* s = which ? sm : sp;
    int L = which ? LM : LP;
    float* wdst = out + (which ? (OFF_MW + b * LM) : (OFF_PW + b * LP));

    __shared__ float red[256];
    float v = (tid < L) ? s[b * L + tid] : -3.4e38f;
    red[tid] = v; __syncthreads();
    for (int off = 128; off > 0; off >>= 1) { if (tid < off) red[tid] = fmaxf(red[tid], red[tid + off]); __syncthreads(); }
    float mx = red[0]; __syncthreads();
    float e = (tid < L) ? expf(v - mx) : 0.f;
    red[tid] = e; __syncthreads();
    for (int off = 128; off > 0; off >>= 1) { if (tid < off) red[tid] += red[tid + off]; __syncthreads(); }
    if (tid < L) wdst[tid] = e / red[0];
}

// ---------------- ctx = sum_l w[l] * enc[b,l,:]; also writes ctx part of XXT ----------------
__global__ void k_ctx(const float* __restrict__ encP, const float* __restrict__ encM,
                      float* __restrict__ out, float* __restrict__ xxt)
{
    int b = blockIdx.y, which = blockIdx.z;
    int d = blockIdx.x * 256 + threadIdx.x;
    const float* enc = which ? encM : encP;
    const float* w = out + (which ? (OFF_MW + b * LM) : (OFF_PW + b * LP));
    int L = which ? LM : LP;
    float acc = 0.f;
    #pragma unroll 8
    for (int l = 0; l < L; ++l) acc += w[l] * enc[(size_t)(b * L + l) * DENC + d];
    out[OFF_CTX + b * 2 * DENC + which * DENC + d] = acc;
    xxt[(H + which * DENC + d) * 16 + b] = acc;
}

// ---------------- logits partials ----------------
__global__ void k_logits_p(const float* __restrict__ xxt, const float* __restrict__ ow,
                           float* __restrict__ lpart)
{
    int v = blockIdx.x * 256 + threadIdx.x;
    int k0 = blockIdx.y * (K1 / LSPLIT);           // chunk 320
    float acc[16];
    #pragma unroll
    for (int b = 0; b < 16; ++b) acc[b] = 0.f;
    #pragma unroll 8
    for (int k = k0; k < k0 + K1 / LSPLIT; ++k) {
        float w = ow[(size_t)k * V + v];
        const float4* xp = (const float4*)&xxt[k * 16];
        float4 x0 = xp[0], x1 = xp[1], x2 = xp[2], x3 = xp[3];
        acc[0]  += x0.x * w; acc[1]  += x0.y * w; acc[2]  += x0.z * w; acc[3]  += x0.w * w;
        acc[4]  += x1.x * w; acc[5]  += x1.y * w; acc[6]  += x1.z * w; acc[7]  += x1.w * w;
        acc[8]  += x2.x * w; acc[9]  += x2.y * w; acc[10] += x2.z * w; acc[11] += x2.w * w;
        acc[12] += x3.x * w; acc[13] += x3.y * w; acc[14] += x3.z * w; acc[15] += x3.w * w;
    }
    #pragma unroll
    for (int b = 0; b < 16; ++b) lpart[((size_t)blockIdx.y * B + b) * V + v] = acc[b];
}

// ---------------- logits reduce + bias ----------------
__global__ void k_logits_r(const float* __restrict__ lpart, const float* __restrict__ ob,
                           float* __restrict__ out)
{
    int v = blockIdx.x * 256 + threadIdx.x;
    int b = blockIdx.y;
    float s = ob[v];
    #pragma unroll
    for (int p = 0; p < LSPLIT; ++p) s += lpart[((size_t)p * B + b) * V + v];
    out[(size_t)b * V + v] = s;
}

extern "C" void kernel_launch(void* const* d_in, const int* in_sizes, int n_in,
                              void* d_out, int out_size, void* d_ws, size_t ws_size,
                              hipStream_t stream)
{
    const int*   word = (const int*)d_in[0];
    const float* encP = (const float*)d_in[1];
    const float* encM = (const float*)d_in[2];
    const float* ctx  = (const float*)d_in[3];
    const float* h1o  = (const float*)d_in[4];
    const float* c1o  = (const float*)d_in[5];
    const float* h2o  = (const float*)d_in[6];
    const float* c2o  = (const float*)d_in[7];
    const float* h3o  = (const float*)d_in[8];
    const float* c3o  = (const float*)d_in[9];
    const float* h4o  = (const float*)d_in[10];
    const float* c4o  = (const float*)d_in[11];
    const float* emb  = (const float*)d_in[12];
    const float* Wx1 = (const float*)d_in[13]; const float* Wh1 = (const float*)d_in[14]; const float* b1 = (const float*)d_in[15];
    const float* Wx2 = (const float*)d_in[16]; const float* Wh2 = (const float*)d_in[17]; const float* b2 = (const float*)d_in[18];
    const float* Wx3 = (const float*)d_in[19]; const float* Wh3 = (const float*)d_in[20]; const float* b3 = (const float*)d_in[21];
    const float* Wx4 = (const float*)d_in[22]; const float* Wh4 = (const float*)d_in[23]; const float* b4 = (const float*)d_in[24];
    const float* pW1w = (const float*)d_in[25]; const float* pW1b = (const float*)d_in[26];
    const float* pW2w = (const float*)d_in[27]; const float* pW2b = (const float*)d_in[28];
    const float* pVw  = (const float*)d_in[29]; const float* pVb  = (const float*)d_in[30];
    const float* mW1w = (const float*)d_in[31]; const float* mW1b = (const float*)d_in[32];
    const float* mW2w = (const float*)d_in[33]; const float* mW2b = (const float*)d_in[34];
    const float* mVw  = (const float*)d_in[35]; const float* mVb  = (const float*)d_in[36];
    const float* outw = (const float*)d_in[37]; const float* outb = (const float*)d_in[38];

    float* out = (float*)d_out;
    float* ws  = (float*)d_ws;
    float* X     = ws + WS_X;
    float* ZPART = ws + WS_ZPART;
    float* D2P   = ws + WS_D2P;
    float* D2M   = ws + WS_D2M;
    float* SP    = ws + WS_SP;
    float* SM    = ws + WS_SM;
    float* XXT   = ws + WS_XXT;
    float* LPART = ws + WS_LPART;
    __hip_bfloat16* ENCBF = (__hip_bfloat16*)(ws + WS_ENCBF);
    __hip_bfloat16* W1T   = (__hip_bfloat16*)(ws + WS_W1T);

    dim3 blk(256);

    // 0. bf16 conversions for the attention GEMM (independent of LSTM chain)
    k_cvt_enc<<<dim3((B * LM * DENC / 4 + 255) / 256, 2), blk, 0, stream>>>(encP, encM, ENCBF);
    k_cvtT<<<dim3(DENC / 64, H / 64, 2), blk, 0, stream>>>(pW1w, mW1w, W1T);

    // 1. embed + concat
    k_embed<<<dim3(B), blk, 0, stream>>>(word, ctx, emb, X);

    // 2. LSTM chain (split-K partials + fused reduce/gates)
    k_lstm_zp<<<dim3(8, ZSPLIT), blk, 0, stream>>>(X, K1, h1o, Wx1, Wh1, ZPART);
    k_gates  <<<dim3(2, B), blk, 0, stream>>>(ZPART, b1, c1o, out + OFF_H1, out + OFF_C1, nullptr);

    k_lstm_zp<<<dim3(8, ZSPLIT), blk, 0, stream>>>(out + OFF_H1, H, h2o, Wx2, Wh2, ZPART);
    k_gates  <<<dim3(2, B), blk, 0, stream>>>(ZPART, b2, c2o, out + OFF_H2, out + OFF_C2, nullptr);

    k_lstm_zp<<<dim3(8, ZSPLIT), blk, 0, stream>>>(out + OFF_H2, H, h3o, Wx3, Wh3, ZPART);
    k_gates  <<<dim3(2, B), blk, 0, stream>>>(ZPART, b3, c3o, out + OFF_H3, out + OFF_C3, nullptr);

    k_lstm_zp<<<dim3(8, ZSPLIT), blk, 0, stream>>>(out + OFF_H3, H, h4o, Wx4, Wh4, ZPART);
    k_gates  <<<dim3(2, B), blk, 0, stream>>>(ZPART, b4, c4o, out + OFF_H4, out + OFF_C4, XXT);

    // 3. attention decoder projections (p and m)
    k_decproj<<<dim3(2, B, 2), blk, 0, stream>>>(out + OFF_H4, pW2w, pW2b, mW2w, mW2b, D2P, D2M);

    // 4. MFMA attention scores
    k_attscore_mfma<<<dim3(32 + 64), blk, 0, stream>>>(
        ENCBF, W1T, pW1b, pVw, pVb, mW1b, mVw, mVb, D2P, D2M, SP, SM);

    // 5. softmax (writes p_w, m_w), then weighted ctx (writes ctx_new + XXT)
    k_softmax<<<dim3(B, 2), blk, 0, stream>>>(SP, SM, out);
    k_ctx<<<dim3(DENC / 256, B, 2), blk, 0, stream>>>(encP, encM, out, XXT);

    // 6. logits = xx @ out_w + out_b (split-K partials + reduce)
    k_logits_p<<<dim3(V / 256, LSPLIT), blk, 0, stream>>>(XXT, outw, LPART);
    k_logits_r<<<dim3(V / 256, B), blk, 0, stream>>>(LPART, outb, out);
}